// Round 11
// baseline (454.329 us; speedup 1.0000x reference)
//
#include <hip/hip_runtime.h>
#include <hip/hip_bf16.h>
#include <math.h>

#define PI_F 3.14159265358979323846f

// ---------------------------------------------------------------------------
// Kernel 1: build the fixed 64x64 complex unitary U (everything after the
// input RY layer). One block per INPUT basis state b (64 blocks x 64 lanes).
// Lane l holds amplitude of flat index l. Qubit q <-> bit (5-q).
// TRANSPOSED store: UT[(j*64 + k)*2 + {0,1}] = {Re,Im} of U[k][j]: for fixed
// input index j, the 64 outputs k are 512 contiguous bytes; the k-chunk slice
// [16c,16c+16) of row j is one aligned 64-byte cache line.
// ---------------------------------------------------------------------------
__global__ __launch_bounds__(64) void build_u(const float* __restrict__ qw,
                                              float* __restrict__ UT) {
    const int l = threadIdx.x;   // amplitude index k (0..63)
    const int b = blockIdx.x;    // input basis state j (0..63)

    float ar = (l == b) ? 1.0f : 0.0f;
    float ai = 0.0f;

    // Phase 2: for i: RX(qw[0][i], i) ; RZ(qw[1][i], i)
    #pragma unroll
    for (int i = 0; i < 6; ++i) {
        const int mask = 1 << (5 - i);
        float th = 0.5f * qw[0 * 6 + i];
        float c = cosf(th), sn = sinf(th);
        float pr = __shfl_xor(ar, mask);
        float pi = __shfl_xor(ai, mask);
        float nr = c * ar + sn * pi;
        float ni = c * ai - sn * pr;
        ar = nr; ai = ni;
        th = 0.5f * qw[1 * 6 + i];
        c = cosf(th); sn = sinf(th);
        float zn = (l & mask) ? 1.0f : -1.0f;
        nr = c * ar - zn * sn * ai;
        ni = c * ai + zn * sn * ar;
        ar = nr; ai = ni;
    }

    // CNOT ring: (0,1),(1,2),(2,3),(3,4),(4,5),(5,0)
    #pragma unroll
    for (int i = 0; i < 6; ++i) {
        const int ctrl = i, tgt = (i + 1) % 6;
        const int cm = 1 << (5 - ctrl), tm = 1 << (5 - tgt);
        float pr = __shfl_xor(ar, tm);
        float pi = __shfl_xor(ai, tm);
        bool take = (l & cm) != 0;
        ar = take ? pr : ar;
        ai = take ? pi : ai;
    }

    // Phase 4: for i: RY(qw[2][i], i) ; RZ(qw[3][i], i)
    #pragma unroll
    for (int i = 0; i < 6; ++i) {
        const int mask = 1 << (5 - i);
        float th = 0.5f * qw[2 * 6 + i];
        float c = cosf(th), sn = sinf(th);
        float pr = __shfl_xor(ar, mask);
        float pi = __shfl_xor(ai, mask);
        float sg = (l & mask) ? sn : -sn;
        float nr = c * ar + sg * pr;
        float ni = c * ai + sg * pi;
        ar = nr; ai = ni;
        th = 0.5f * qw[3 * 6 + i];
        c = cosf(th); sn = sinf(th);
        float zn = (l & mask) ? 1.0f : -1.0f;
        nr = c * ar - zn * sn * ai;
        ni = c * ai + zn * sn * ar;
        ar = nr; ai = ni;
    }

    // CNOTs (0,1),(2,3),(4,5)
    #pragma unroll
    for (int i = 0; i < 6; i += 2) {
        const int cm = 1 << (5 - i), tm = 1 << (5 - (i + 1));
        float pr = __shfl_xor(ar, tm);
        float pi = __shfl_xor(ai, tm);
        bool take = (l & cm) != 0;
        ar = take ? pr : ar;
        ai = take ? pi : ai;
    }

    // Phase 6: RX(qw[4][i], i)
    #pragma unroll
    for (int i = 0; i < 6; ++i) {
        const int mask = 1 << (5 - i);
        float th = 0.5f * qw[4 * 6 + i];
        float c = cosf(th), sn = sinf(th);
        float pr = __shfl_xor(ar, mask);
        float pi = __shfl_xor(ai, mask);
        float nr = c * ar + sn * pi;
        float ni = c * ai - sn * pr;
        ar = nr; ai = ni;
    }

    UT[(b * 64 + l) * 2 + 0] = ar;   // row j=b, col k=l (transposed)
    UT[(b * 64 + l) * 2 + 1] = ai;
}

// ---------------------------------------------------------------------------
// Kernel 2: thread-per-sample fused pipeline, L1-CAPTURE execution shape.
// Mechanism of the former ~250us wall: uniform broadcast VMEM loads do not
// coalesce across waves; resident waves at different k-chunk positions blow
// the 32 KB L1, so every wave streams U (32 KB) from L2 => 8.6 GB of L2 reads.
// Fix: ONE 1024-thread block per CU (grid = B/1024 = 256 = #CUs, LDS 0) and a
// __syncthreads() at each k-chunk boundary, so all 16 waves of the CU read
// the SAME 4 KB U-slice (64 aligned 64B lines) => L1 hits after first touch.
// L2 U-traffic: 8.6 GB -> 256 x 32 KB = 8 MB. Math identical to R3/R10
// (verified absmax 1.95e-3). No early returns (clamped loads, guarded store).
// ---------------------------------------------------------------------------
__global__ __launch_bounds__(1024) void fused_main(
    const float* __restrict__ x,
    const float* __restrict__ W1, const float* __restrict__ b1,
    const float* __restrict__ W2, const float* __restrict__ b2,
    const float* __restrict__ W3, const float* __restrict__ b3,
    const float* __restrict__ W4, const float* __restrict__ b4,
    const float* __restrict__ W5, const float* __restrict__ b5,
    const float* __restrict__ Umat,
    float* __restrict__ out, int B)
{
    const int tid = threadIdx.x;
    const int s   = blockIdx.x * 1024 + tid;
    const int s_ld = (s < B) ? s : (B - 1);   // select, NOT a branch

    // ---- Layer 1: h1 = relu(x[s,:] @ W1 + b1)   (128 -> 32)
    float h1[32];
    #pragma unroll
    for (int o = 0; o < 32; ++o) h1[o] = b1[o];
    const float4* x4 = reinterpret_cast<const float4*>(x + (size_t)s_ld * 128);
    #pragma unroll 2
    for (int j4 = 0; j4 < 32; ++j4) {
        float4 xv = x4[j4];
        const float* w = W1 + j4 * 4 * 32;   // uniform address (broadcast)
        #pragma unroll
        for (int o = 0; o < 32; ++o) h1[o] = fmaf(xv.x, w[o], h1[o]);
        #pragma unroll
        for (int o = 0; o < 32; ++o) h1[o] = fmaf(xv.y, w[32 + o], h1[o]);
        #pragma unroll
        for (int o = 0; o < 32; ++o) h1[o] = fmaf(xv.z, w[64 + o], h1[o]);
        #pragma unroll
        for (int o = 0; o < 32; ++o) h1[o] = fmaf(xv.w, w[96 + o], h1[o]);
    }
    #pragma unroll
    for (int o = 0; o < 32; ++o) h1[o] = fmaxf(h1[o], 0.0f);

    // ---- Layer 2: h2 = relu(h1 @ W2 + b2)   (32 -> 16)
    float h2[16];
    #pragma unroll
    for (int o = 0; o < 16; ++o) h2[o] = b2[o];
    #pragma unroll
    for (int j = 0; j < 32; ++j) {
        #pragma unroll
        for (int o = 0; o < 16; ++o) h2[o] = fmaf(h1[j], W2[j * 16 + o], h2[o]);
    }
    #pragma unroll
    for (int o = 0; o < 16; ++o) h2[o] = fmaxf(h2[o], 0.0f);

    // ---- Layer 3: angles -> half-angle cos/sin per qubit
    float cq[6], sq[6];
    #pragma unroll
    for (int q = 0; q < 6; ++q) {
        float t = b3[q];
        #pragma unroll
        for (int j = 0; j < 16; ++j) t = fmaf(h2[j], W3[j * 6 + q], t);
        t = tanhf(t);
        t = fminf(1.0f, fmaxf(-1.0f, t));
        float half = t * (0.5f * PI_F);
        sq[q] = sinf(half);
        cq[q] = cosf(half);
    }

    // ---- 8-entry half-product tables: psi[j] = hi[j>>3] * lo[j&7]
    float lo[8], hi[8];
    {
        float f3[2] = {cq[3], sq[3]};
        float f4[2] = {cq[4], sq[4]};
        float f5[2] = {cq[5], sq[5]};
        #pragma unroll
        for (int m = 0; m < 8; ++m)
            lo[m] = f3[(m >> 2) & 1] * f4[(m >> 1) & 1] * f5[m & 1];
        float f0[2] = {cq[0], sq[0]};
        float f1[2] = {cq[1], sq[1]};
        float f2[2] = {cq[2], sq[2]};
        #pragma unroll
        for (int m = 0; m < 8; ++m)
            hi[m] = f0[(m >> 2) & 1] * f1[(m >> 1) & 1] * f2[m & 1];
    }

    // ---- GEMV phi = U*psi, k-chunked: 8 chunks of 8 complex outputs.
    // Chunk c, row j: 16 floats at Umat + j*128 + c*16 (one 64B line).
    // The barrier keeps all 16 waves of this CU on the same chunk slice.
    float acc0 = 0.f, acc1 = 0.f, acc2 = 0.f, acc3 = 0.f, acc4 = 0.f, acc5 = 0.f;

    #pragma unroll 1
    for (int c = 0; c < 8; ++c) {
        __syncthreads();                      // align wave progress -> L1 reuse
        const float* ub = Umat + c * 16;      // uniform base for this chunk
        float re[8], im[8];
        #pragma unroll
        for (int kk = 0; kk < 8; ++kk) { re[kk] = 0.0f; im[kk] = 0.0f; }

        #pragma unroll
        for (int jh = 0; jh < 8; ++jh) {
            #pragma unroll
            for (int jl = 0; jl < 8; ++jl) {
                float v = hi[jh] * lo[jl];                  // per-lane VGPR
                const float* u = ub + (jh * 8 + jl) * 128;  // uniform
                #pragma unroll
                for (int kk = 0; kk < 8; ++kk) {
                    re[kk] = fmaf(u[2 * kk],     v, re[kk]);
                    im[kk] = fmaf(u[2 * kk + 1], v, im[kk]);
                }
            }
        }

        // epilogue: kg = 8c+kk ; sign bits 5..3 from c, bits 2..0 from kk
        float s0 = (c & 4) ? -1.0f : 1.0f;
        float s1 = (c & 2) ? -1.0f : 1.0f;
        float s2 = (c & 1) ? -1.0f : 1.0f;
        #pragma unroll
        for (int kk = 0; kk < 8; ++kk) {
            float p = re[kk] * re[kk] + im[kk] * im[kk];
            acc0 = fmaf(s0, p, acc0);
            acc1 = fmaf(s1, p, acc1);
            acc2 = fmaf(s2, p, acc2);
            acc3 += (kk & 4) ? -p : p;
            acc4 += (kk & 2) ? -p : p;
            acc5 += (kk & 1) ? -p : p;
        }
    }

    float qv[6] = {acc0, acc1, acc2, acc3, acc4, acc5};

    // ---- Layer 4: h4 = relu(q_out @ W4 + b4)   (6 -> 16)
    float h4[16];
    #pragma unroll
    for (int o = 0; o < 16; ++o) h4[o] = b4[o];
    #pragma unroll
    for (int q = 0; q < 6; ++q) {
        #pragma unroll
        for (int o = 0; o < 16; ++o) h4[o] = fmaf(qv[q], W4[q * 16 + o], h4[o]);
    }
    #pragma unroll
    for (int o = 0; o < 16; ++o) h4[o] = fmaxf(h4[o], 0.0f);

    // ---- Layer 5: out = h4 @ W5 + b5   (16 -> 20)
    float o5[20];
    #pragma unroll
    for (int o = 0; o < 20; ++o) {
        float t = b5[o];
        #pragma unroll
        for (int j = 0; j < 16; ++j) t = fmaf(h4[j], W5[j * 20 + o], t);
        o5[o] = t;
    }

    // Only divergent control flow in the kernel: the final store guard.
    if (s < B) {
        float4* outv = reinterpret_cast<float4*>(out + (size_t)s * 20);
        #pragma unroll
        for (int i = 0; i < 5; ++i)
            outv[i] = make_float4(o5[4 * i], o5[4 * i + 1], o5[4 * i + 2], o5[4 * i + 3]);
    }
}

// ---------------------------------------------------------------------------
extern "C" void kernel_launch(void* const* d_in, const int* in_sizes, int n_in,
                              void* d_out, int out_size, void* d_ws, size_t ws_size,
                              hipStream_t stream) {
    const float* x  = (const float*)d_in[0];
    const float* W1 = (const float*)d_in[1];
    const float* b1 = (const float*)d_in[2];
    const float* W2 = (const float*)d_in[3];
    const float* b2 = (const float*)d_in[4];
    const float* W3 = (const float*)d_in[5];
    const float* b3 = (const float*)d_in[6];
    const float* qw = (const float*)d_in[7];
    const float* W4 = (const float*)d_in[8];
    const float* b4 = (const float*)d_in[9];
    const float* W5 = (const float*)d_in[10];
    const float* b5 = (const float*)d_in[11];
    float* out = (float*)d_out;
    float* UT  = (float*)d_ws;   // 64*64*2 floats = 32 KB

    const int B = in_sizes[0] / 128;

    build_u<<<64, 64, 0, stream>>>(qw, UT);
    fused_main<<<(B + 1023) / 1024, 1024, 0, stream>>>(
        x, W1, b1, W2, b2, W3, b3, W4, b4, W5, b5, UT, out, B);
}

// Round 12
// 140.019 us; speedup vs baseline: 3.2448x; 3.2448x over previous
//
#include <hip/hip_runtime.h>
#include <hip/hip_bf16.h>
#include <math.h>

#define PI_F 3.14159265358979323846f

// ---------------------------------------------------------------------------
// Kernel 1: build the fixed 64x64 complex unitary U. One block per INPUT
// basis state b. Layout: Umat[(j*64 + k)*2 + {0,1}] = {Re,Im} of U[k][j];
// the chunk slice [16c,16c+16) of row j is one aligned 64-byte line.
// ---------------------------------------------------------------------------
__global__ __launch_bounds__(64) void build_u(const float* __restrict__ qw,
                                              float* __restrict__ Umat) {
    const int l = threadIdx.x;   // amplitude index k (0..63)
    const int b = blockIdx.x;    // input basis state j (0..63)

    float ar = (l == b) ? 1.0f : 0.0f;
    float ai = 0.0f;

    #pragma unroll
    for (int i = 0; i < 6; ++i) {
        const int mask = 1 << (5 - i);
        float th = 0.5f * qw[0 * 6 + i];
        float c = cosf(th), sn = sinf(th);
        float pr = __shfl_xor(ar, mask);
        float pi = __shfl_xor(ai, mask);
        float nr = c * ar + sn * pi;
        float ni = c * ai - sn * pr;
        ar = nr; ai = ni;
        th = 0.5f * qw[1 * 6 + i];
        c = cosf(th); sn = sinf(th);
        float zn = (l & mask) ? 1.0f : -1.0f;
        nr = c * ar - zn * sn * ai;
        ni = c * ai + zn * sn * ar;
        ar = nr; ai = ni;
    }

    #pragma unroll
    for (int i = 0; i < 6; ++i) {
        const int ctrl = i, tgt = (i + 1) % 6;
        const int cm = 1 << (5 - ctrl), tm = 1 << (5 - tgt);
        float pr = __shfl_xor(ar, tm);
        float pi = __shfl_xor(ai, tm);
        bool take = (l & cm) != 0;
        ar = take ? pr : ar;
        ai = take ? pi : ai;
    }

    #pragma unroll
    for (int i = 0; i < 6; ++i) {
        const int mask = 1 << (5 - i);
        float th = 0.5f * qw[2 * 6 + i];
        float c = cosf(th), sn = sinf(th);
        float pr = __shfl_xor(ar, mask);
        float pi = __shfl_xor(ai, mask);
        float sg = (l & mask) ? sn : -sn;
        float nr = c * ar + sg * pr;
        float ni = c * ai + sg * pi;
        ar = nr; ai = ni;
        th = 0.5f * qw[3 * 6 + i];
        c = cosf(th); sn = sinf(th);
        float zn = (l & mask) ? 1.0f : -1.0f;
        nr = c * ar - zn * sn * ai;
        ni = c * ai + zn * sn * ar;
        ar = nr; ai = ni;
    }

    #pragma unroll
    for (int i = 0; i < 6; i += 2) {
        const int cm = 1 << (5 - i), tm = 1 << (5 - (i + 1));
        float pr = __shfl_xor(ar, tm);
        float pi = __shfl_xor(ai, tm);
        bool take = (l & cm) != 0;
        ar = take ? pr : ar;
        ai = take ? pi : ai;
    }

    #pragma unroll
    for (int i = 0; i < 6; ++i) {
        const int mask = 1 << (5 - i);
        float th = 0.5f * qw[4 * 6 + i];
        float c = cosf(th), sn = sinf(th);
        float pr = __shfl_xor(ar, mask);
        float pi = __shfl_xor(ai, mask);
        float nr = c * ar + sn * pi;
        float ni = c * ai - sn * pr;
        ar = nr; ai = ni;
    }

    Umat[(b * 64 + l) * 2 + 0] = ar;
    Umat[(b * 64 + l) * 2 + 1] = ai;
}

// ---------------------------------------------------------------------------
// Common device helpers (shared math, verified absmax 1.95e-3 since R3)
// ---------------------------------------------------------------------------
__device__ __forceinline__ void front_mlp(
    const float* __restrict__ x, int s_ld,
    const float* __restrict__ W1, const float* __restrict__ b1,
    const float* __restrict__ W2, const float* __restrict__ b2,
    const float* __restrict__ W3, const float* __restrict__ b3,
    float lo[8], float hi[8])
{
    // Layer 1: 128 -> 32
    float h1[32];
    #pragma unroll
    for (int o = 0; o < 32; ++o) h1[o] = b1[o];
    const float4* x4 = reinterpret_cast<const float4*>(x + (size_t)s_ld * 128);
    #pragma unroll 2
    for (int j4 = 0; j4 < 32; ++j4) {
        float4 xv = x4[j4];
        const float* w = W1 + j4 * 4 * 32;
        #pragma unroll
        for (int o = 0; o < 32; ++o) h1[o] = fmaf(xv.x, w[o], h1[o]);
        #pragma unroll
        for (int o = 0; o < 32; ++o) h1[o] = fmaf(xv.y, w[32 + o], h1[o]);
        #pragma unroll
        for (int o = 0; o < 32; ++o) h1[o] = fmaf(xv.z, w[64 + o], h1[o]);
        #pragma unroll
        for (int o = 0; o < 32; ++o) h1[o] = fmaf(xv.w, w[96 + o], h1[o]);
    }
    #pragma unroll
    for (int o = 0; o < 32; ++o) h1[o] = fmaxf(h1[o], 0.0f);

    // Layer 2: 32 -> 16
    float h2[16];
    #pragma unroll
    for (int o = 0; o < 16; ++o) h2[o] = b2[o];
    #pragma unroll
    for (int j = 0; j < 32; ++j) {
        #pragma unroll
        for (int o = 0; o < 16; ++o) h2[o] = fmaf(h1[j], W2[j * 16 + o], h2[o]);
    }
    #pragma unroll
    for (int o = 0; o < 16; ++o) h2[o] = fmaxf(h2[o], 0.0f);

    // Layer 3: angles -> half-angle cos/sin
    float cq[6], sq[6];
    #pragma unroll
    for (int q = 0; q < 6; ++q) {
        float t = b3[q];
        #pragma unroll
        for (int j = 0; j < 16; ++j) t = fmaf(h2[j], W3[j * 6 + q], t);
        t = tanhf(t);
        t = fminf(1.0f, fmaxf(-1.0f, t));
        float half = t * (0.5f * PI_F);
        sq[q] = sinf(half);
        cq[q] = cosf(half);
    }

    // half-product tables: psi[j] = hi[j>>3] * lo[j&7]
    {
        float f3[2] = {cq[3], sq[3]};
        float f4[2] = {cq[4], sq[4]};
        float f5[2] = {cq[5], sq[5]};
        #pragma unroll
        for (int m = 0; m < 8; ++m)
            lo[m] = f3[(m >> 2) & 1] * f4[(m >> 1) & 1] * f5[m & 1];
        float f0[2] = {cq[0], sq[0]};
        float f1[2] = {cq[1], sq[1]};
        float f2[2] = {cq[2], sq[2]};
        #pragma unroll
        for (int m = 0; m < 8; ++m)
            hi[m] = f0[(m >> 2) & 1] * f1[(m >> 1) & 1] * f2[m & 1];
    }
}

__device__ __forceinline__ void gemv_and_back(
    const float lo[8], const float hi[8],
    const float* __restrict__ Umat,
    const float* __restrict__ W4, const float* __restrict__ b4,
    const float* __restrict__ W5, const float* __restrict__ b5,
    float* __restrict__ out, int s, int B)
{
    float acc0 = 0.f, acc1 = 0.f, acc2 = 0.f, acc3 = 0.f, acc4 = 0.f, acc5 = 0.f;

    #pragma unroll 1
    for (int c = 0; c < 8; ++c) {
        const float* ub = Umat + c * 16;      // uniform base for this chunk
        float re[8], im[8];
        #pragma unroll
        for (int kk = 0; kk < 8; ++kk) { re[kk] = 0.0f; im[kk] = 0.0f; }

        #pragma unroll
        for (int jh = 0; jh < 8; ++jh) {
            #pragma unroll
            for (int jl = 0; jl < 8; ++jl) {
                float v = hi[jh] * lo[jl];
                const float* u = ub + (jh * 8 + jl) * 128;  // uniform -> broadcast
                #pragma unroll
                for (int kk = 0; kk < 8; ++kk) {
                    re[kk] = fmaf(u[2 * kk],     v, re[kk]);
                    im[kk] = fmaf(u[2 * kk + 1], v, im[kk]);
                }
            }
        }

        float s0 = (c & 4) ? -1.0f : 1.0f;
        float s1 = (c & 2) ? -1.0f : 1.0f;
        float s2 = (c & 1) ? -1.0f : 1.0f;
        #pragma unroll
        for (int kk = 0; kk < 8; ++kk) {
            float p = re[kk] * re[kk] + im[kk] * im[kk];
            acc0 = fmaf(s0, p, acc0);
            acc1 = fmaf(s1, p, acc1);
            acc2 = fmaf(s2, p, acc2);
            acc3 += (kk & 4) ? -p : p;
            acc4 += (kk & 2) ? -p : p;
            acc5 += (kk & 1) ? -p : p;
        }
    }

    float qv[6] = {acc0, acc1, acc2, acc3, acc4, acc5};

    float h4[16];
    #pragma unroll
    for (int o = 0; o < 16; ++o) h4[o] = b4[o];
    #pragma unroll
    for (int q = 0; q < 6; ++q) {
        #pragma unroll
        for (int o = 0; o < 16; ++o) h4[o] = fmaf(qv[q], W4[q * 16 + o], h4[o]);
    }
    #pragma unroll
    for (int o = 0; o < 16; ++o) h4[o] = fmaxf(h4[o], 0.0f);

    float o5[20];
    #pragma unroll
    for (int o = 0; o < 20; ++o) {
        float t = b5[o];
        #pragma unroll
        for (int j = 0; j < 16; ++j) t = fmaf(h4[j], W5[j * 20 + o], t);
        o5[o] = t;
    }

    if (s < B) {
        float4* outv = reinterpret_cast<float4*>(out + (size_t)s * 20);
        #pragma unroll
        for (int i = 0; i < 5; ++i)
            outv[i] = make_float4(o5[4 * i], o5[4 * i + 1], o5[4 * i + 2], o5[4 * i + 3]);
    }
}

// ---------------------------------------------------------------------------
// Split path, kernel A: front MLP -> 16 table floats per sample, written as
// 16 SoA planes tab[i*B + s] (both sides coalesced). Peak VGPR: h1 phase
// (~50) -> target <=64 => 8 waves/SIMD hides x/W load latency.
// ---------------------------------------------------------------------------
__global__ __launch_bounds__(256) void front_kernel(
    const float* __restrict__ x,
    const float* __restrict__ W1, const float* __restrict__ b1,
    const float* __restrict__ W2, const float* __restrict__ b2,
    const float* __restrict__ W3, const float* __restrict__ b3,
    float* __restrict__ tab, int B)
{
    const int s = blockIdx.x * 256 + threadIdx.x;
    const int s_ld = (s < B) ? s : (B - 1);

    float lo[8], hi[8];
    front_mlp(x, s_ld, W1, b1, W2, b2, W3, b3, lo, hi);

    if (s < B) {
        #pragma unroll
        for (int i = 0; i < 8; ++i) tab[(size_t)i * B + s] = lo[i];
        #pragma unroll
        for (int i = 0; i < 8; ++i) tab[(size_t)(8 + i) * B + s] = hi[i];
    }
}

// ---------------------------------------------------------------------------
// Split path, kernel B: GEMV + back MLP only. Live state: 16 acc + 16 table
// + 6 q + addressing => target <=64 VGPR => 8 waves/SIMD so the uniform
// broadcast U loads' L1/L2 latency is hidden by TLP (the R3..R10 wall).
// ---------------------------------------------------------------------------
__global__ __launch_bounds__(256) void gemv_kernel(
    const float* __restrict__ tab,
    const float* __restrict__ Umat,
    const float* __restrict__ W4, const float* __restrict__ b4,
    const float* __restrict__ W5, const float* __restrict__ b5,
    float* __restrict__ out, int B)
{
    const int s = blockIdx.x * 256 + threadIdx.x;
    const int s_ld = (s < B) ? s : (B - 1);

    float lo[8], hi[8];
    #pragma unroll
    for (int i = 0; i < 8; ++i) lo[i] = tab[(size_t)i * B + s_ld];
    #pragma unroll
    for (int i = 0; i < 8; ++i) hi[i] = tab[(size_t)(8 + i) * B + s_ld];

    gemv_and_back(lo, hi, Umat, W4, b4, W5, b5, out, s, B);
}

// ---------------------------------------------------------------------------
// Fallback single kernel (R10, verified): used only if ws_size is too small
// for the table planes.
// ---------------------------------------------------------------------------
__global__ __launch_bounds__(256) void fused_single(
    const float* __restrict__ x,
    const float* __restrict__ W1, const float* __restrict__ b1,
    const float* __restrict__ W2, const float* __restrict__ b2,
    const float* __restrict__ W3, const float* __restrict__ b3,
    const float* __restrict__ W4, const float* __restrict__ b4,
    const float* __restrict__ W5, const float* __restrict__ b5,
    const float* __restrict__ Umat,
    float* __restrict__ out, int B)
{
    const int s = blockIdx.x * 256 + threadIdx.x;
    const int s_ld = (s < B) ? s : (B - 1);

    float lo[8], hi[8];
    front_mlp(x, s_ld, W1, b1, W2, b2, W3, b3, lo, hi);
    gemv_and_back(lo, hi, Umat, W4, b4, W5, b5, out, s, B);
}

// ---------------------------------------------------------------------------
extern "C" void kernel_launch(void* const* d_in, const int* in_sizes, int n_in,
                              void* d_out, int out_size, void* d_ws, size_t ws_size,
                              hipStream_t stream) {
    const float* x  = (const float*)d_in[0];
    const float* W1 = (const float*)d_in[1];
    const float* b1 = (const float*)d_in[2];
    const float* W2 = (const float*)d_in[3];
    const float* b2 = (const float*)d_in[4];
    const float* W3 = (const float*)d_in[5];
    const float* b3 = (const float*)d_in[6];
    const float* qw = (const float*)d_in[7];
    const float* W4 = (const float*)d_in[8];
    const float* b4 = (const float*)d_in[9];
    const float* W5 = (const float*)d_in[10];
    const float* b5 = (const float*)d_in[11];
    float* out = (float*)d_out;

    const int B = in_sizes[0] / 128;
    const int nblk = (B + 255) / 256;

    float* Umat = (float*)d_ws;                       // 32 KB
    float* tab  = (float*)d_ws + 8192;                // 16 * B floats
    const size_t need = 8192u * 4 + (size_t)16 * 4 * (size_t)B;

    build_u<<<64, 64, 0, stream>>>(qw, Umat);

    if (ws_size >= need) {
        front_kernel<<<nblk, 256, 0, stream>>>(x, W1, b1, W2, b2, W3, b3, tab, B);
        gemv_kernel<<<nblk, 256, 0, stream>>>(tab, Umat, W4, b4, W5, b5, out, B);
    } else {
        fused_single<<<nblk, 256, 0, stream>>>(
            x, W1, b1, W2, b2, W3, b3, W4, b4, W5, b5, Umat, out, B);
    }
}